// Round 1
// baseline (153.328 us; speedup 1.0000x reference)
//
#include <hip/hip_runtime.h>

#define E_  1024
#define H_  16
#define DH_ 64
#define B_  2
#define T_  2048
#define BT_ (B_*T_)   // 4096

typedef __bf16 bf16x8 __attribute__((ext_vector_type(8)));
typedef float  f32x4  __attribute__((ext_vector_type(4)));
typedef unsigned short u16x8 __attribute__((ext_vector_type(8)));
typedef unsigned short u16x4 __attribute__((ext_vector_type(4)));

static __device__ __forceinline__ unsigned short f2bf(float x){
  unsigned int u = __float_as_uint(x);
  u += 0x7fffu + ((u >> 16) & 1u);
  return (unsigned short)(u >> 16);
}
static __device__ __forceinline__ float bf2f(unsigned short s){
  return __uint_as_float(((unsigned int)s) << 16);
}

__global__ __launch_bounds__(256)
void cast_f32_bf16(const float* __restrict__ in, unsigned short* __restrict__ out, int n){
  int i = (blockIdx.x * 256 + threadIdx.x) * 4;
  if (i >= n) return;
  float4 v = *(const float4*)(in + i);
  u16x4 o;
  o[0] = f2bf(v.x); o[1] = f2bf(v.y); o[2] = f2bf(v.z); o[3] = f2bf(v.w);
  *(u16x4*)(out + i) = o;
}

static __device__ __forceinline__ void store_val(float* p, float v){ *p = v; }
static __device__ __forceinline__ void store_val(unsigned short* p, float v){ *p = f2bf(v); }

// C[i,j] = (sum_e A[i,e]*Bw[j,e] + bias[j]) * scale
// A: [M,K] bf16 row-major; Bw: [N,K] bf16 row-major (weights, NT gemm)
// BM=128, BN=64, BK=32; 4 waves as 2x2, wave tile 64x32 (4x2 frags of 16x16)
template<typename OutT>
__global__ __launch_bounds__(256)
void gemm_nt(const unsigned short* __restrict__ A,
             const unsigned short* __restrict__ Bw,
             const float* __restrict__ bias,
             OutT* __restrict__ C,
             int M, int N, int K, float scale)
{
  __shared__ unsigned short Asl[128][40];   // +8 pad (16B) keeps b128 alignment, spreads banks
  __shared__ unsigned short Bsl[64][40];
  const int tid  = threadIdx.x;
  const int bm   = blockIdx.x;
  const int bn   = blockIdx.y;
  const int wid  = tid >> 6;
  const int lane = tid & 63;
  const int wr   = wid >> 1, wc = wid & 1;
  const int lr   = lane & 15;
  const int lk   = (lane >> 4) * 8;

  f32x4 acc[4][2];
  #pragma unroll
  for (int m = 0; m < 4; ++m)
    #pragma unroll
    for (int n = 0; n < 2; ++n)
      acc[m][n] = (f32x4){0.f, 0.f, 0.f, 0.f};

  const size_t arow0 = (size_t)bm * 128;
  const size_t brow0 = (size_t)bn * 64;

  for (int k0 = 0; k0 < K; k0 += 32) {
    // stage A tile: 128 rows x 32 cols = 512 chunks of 8 bf16
    int c   = tid;
    int row = c >> 2, off = (c & 3) * 8;
    *(u16x8*)&Asl[row][off] = *(const u16x8*)(A + (arow0 + row) * K + k0 + off);
    c = tid + 256;
    row = c >> 2; off = (c & 3) * 8;
    *(u16x8*)&Asl[row][off] = *(const u16x8*)(A + (arow0 + row) * K + k0 + off);
    // stage B tile: 64 rows x 32 cols = 256 chunks
    row = tid >> 2; off = (tid & 3) * 8;
    *(u16x8*)&Bsl[row][off] = *(const u16x8*)(Bw + (brow0 + row) * K + k0 + off);
    __syncthreads();

    bf16x8 af[4], bfr[2];
    #pragma unroll
    for (int m = 0; m < 4; ++m) af[m]  = *(const bf16x8*)&Asl[wr*64 + m*16 + lr][lk];
    #pragma unroll
    for (int n = 0; n < 2; ++n) bfr[n] = *(const bf16x8*)&Bsl[wc*32 + n*16 + lr][lk];
    #pragma unroll
    for (int m = 0; m < 4; ++m)
      #pragma unroll
      for (int n = 0; n < 2; ++n)
        acc[m][n] = __builtin_amdgcn_mfma_f32_16x16x32_bf16(af[m], bfr[n], acc[m][n], 0, 0, 0);
    __syncthreads();
  }

  // epilogue: C/D layout col=lane&15, row=(lane>>4)*4+reg
  #pragma unroll
  for (int n = 0; n < 2; ++n) {
    int col = bn*64 + wc*32 + n*16 + lr;
    float bv = bias[col];
    #pragma unroll
    for (int m = 0; m < 4; ++m) {
      int row0 = bm*128 + wr*64 + m*16 + (lane >> 4) * 4;
      #pragma unroll
      for (int r = 0; r < 4; ++r) {
        float v = (acc[m][n][r] + bv) * scale;
        store_val(&C[(size_t)(row0 + r) * N + col], v);
      }
    }
  }
}

// Partial M[d1][d2] = sum_{t in chunk} K[b,t,h*64+d1] * V[b,t,h*64+d2]
// grid (B*H, 8), block 256. Each chunk = 256 t-rows, staged 32 at a time.
__global__ __launch_bounds__(256)
void ktv_partial(const unsigned short* __restrict__ Kmat,
                 const unsigned short* __restrict__ Vmat,
                 float* __restrict__ Mpart)
{
  __shared__ float Ks[32][64];
  __shared__ float Vs[32][64];
  const int tid   = threadIdx.x;
  const int bh    = blockIdx.x;   // 0..31
  const int chunk = blockIdx.y;   // 0..7
  const int b = bh >> 4, h = bh & 15;
  const int d2  = tid & 63;
  const int d1b = (tid >> 6) * 16;
  float acc[16];
  #pragma unroll
  for (int i = 0; i < 16; ++i) acc[i] = 0.f;
  const int row = tid >> 3, off = (tid & 7) * 8;
  const size_t base = ((size_t)b * T_) * E_ + (size_t)h * 64;

  for (int t0 = chunk * 256; t0 < chunk * 256 + 256; t0 += 32) {
    u16x8 kv = *(const u16x8*)(Kmat + base + (size_t)(t0 + row) * E_ + off);
    u16x8 vv = *(const u16x8*)(Vmat + base + (size_t)(t0 + row) * E_ + off);
    #pragma unroll
    for (int j = 0; j < 8; ++j) { Ks[row][off+j] = bf2f(kv[j]); Vs[row][off+j] = bf2f(vv[j]); }
    __syncthreads();
    for (int tt = 0; tt < 32; ++tt) {
      float vvv = Vs[tt][d2];
      #pragma unroll
      for (int i = 0; i < 16; ++i) acc[i] += Ks[tt][d1b + i] * vvv;
    }
    __syncthreads();
  }
  float* mp = Mpart + ((size_t)bh * 8 + chunk) * 4096;
  #pragma unroll
  for (int i = 0; i < 16; ++i) mp[(d1b + i) * 64 + d2] = acc[i];
}

// M_final = (sum_chunks Mpart) / 8   (the scores' 1/sqrt(DH))
__global__ __launch_bounds__(256)
void ktv_reduce(const float* __restrict__ Mpart, float* __restrict__ Mfin){
  const int bh = blockIdx.x;
  for (int i = threadIdx.x; i < 4096; i += 256) {
    float s = 0.f;
    #pragma unroll
    for (int c = 0; c < 8; ++c) s += Mpart[((size_t)bh * 8 + c) * 4096 + i];
    Mfin[(size_t)bh * 4096 + i] = s * 0.125f;
  }
}

// O[b,t,h*64+d2] = sum_d1 Q[b,t,h*64+d1] * M[b,h][d1][d2]
// grid (B*T/32, H), block 256: 32 t-rows per block.
__global__ __launch_bounds__(256)
void qm_kernel(const unsigned short* __restrict__ Q,
               const float* __restrict__ Mfin,
               unsigned short* __restrict__ O)
{
  __shared__ float Ms[64][64];
  __shared__ float Qs[32][64];
  const int tid = threadIdx.x;
  const int rb  = blockIdx.x;    // 0..127
  const int h   = blockIdx.y;
  const int b   = rb >> 6;
  const int t0  = (rb & 63) * 32;
  const float* mf = Mfin + ((size_t)(b * 16 + h)) * 4096;
  for (int i = tid; i < 4096; i += 256) Ms[i >> 6][i & 63] = mf[i];
  const int row = tid >> 3, off = (tid & 7) * 8;
  const size_t base = ((size_t)b * T_) * E_ + (size_t)h * 64;
  u16x8 qv = *(const u16x8*)(Q + base + (size_t)(t0 + row) * E_ + off);
  #pragma unroll
  for (int j = 0; j < 8; ++j) Qs[row][off + j] = bf2f(qv[j]);
  __syncthreads();
  const int d2 = tid & 63;
  const int r0 = (tid >> 6) * 8;
  for (int rr = r0; rr < r0 + 8; ++rr) {
    float s = 0.f;
    #pragma unroll
    for (int d1 = 0; d1 < 64; ++d1) s += Qs[rr][d1] * Ms[d1][d2];
    O[base + (size_t)(t0 + rr) * E_ + d2] = f2bf(s);
  }
}

extern "C" void kernel_launch(void* const* d_in, const int* in_sizes, int n_in,
                              void* d_out, int out_size, void* d_ws, size_t ws_size,
                              hipStream_t stream)
{
  const float* hidden = (const float*)d_in[0];
  const float* Wq = (const float*)d_in[1];
  const float* bq = (const float*)d_in[2];
  const float* Wk = (const float*)d_in[3];
  const float* bk = (const float*)d_in[4];
  const float* Wv = (const float*)d_in[5];
  const float* bv = (const float*)d_in[6];
  const float* Wo = (const float*)d_in[7];
  const float* bo = (const float*)d_in[8];
  float* out = (float*)d_out;

  const size_t SZ_ACT = (size_t)BT_ * E_;   // 4M elems
  const size_t SZ_W   = (size_t)E_ * E_;    // 1M elems

  char* p = (char*)d_ws;
  unsigned short* hb  = (unsigned short*)p; p += SZ_ACT * 2;
  unsigned short* wqb = (unsigned short*)p; p += SZ_W * 2;
  unsigned short* wkb = (unsigned short*)p; p += SZ_W * 2;
  unsigned short* wvb = (unsigned short*)p; p += SZ_W * 2;
  unsigned short* wob = (unsigned short*)p; p += SZ_W * 2;
  unsigned short* qb  = (unsigned short*)p; p += SZ_ACT * 2;
  unsigned short* kb  = (unsigned short*)p; p += SZ_ACT * 2;
  unsigned short* vb  = (unsigned short*)p; p += SZ_ACT * 2;
  unsigned short* ob  = (unsigned short*)p; p += SZ_ACT * 2;
  float* Mpart = (float*)p; p += (size_t)32 * 8 * 4096 * 4;
  float* Mfin  = (float*)p; p += (size_t)32 * 4096 * 4;

  cast_f32_bf16<<<(int)(SZ_ACT / 1024), 256, 0, stream>>>(hidden, hb, (int)SZ_ACT);
  cast_f32_bf16<<<(int)(SZ_W  / 1024), 256, 0, stream>>>(Wq, wqb, (int)SZ_W);
  cast_f32_bf16<<<(int)(SZ_W  / 1024), 256, 0, stream>>>(Wk, wkb, (int)SZ_W);
  cast_f32_bf16<<<(int)(SZ_W  / 1024), 256, 0, stream>>>(Wv, wvb, (int)SZ_W);
  cast_f32_bf16<<<(int)(SZ_W  / 1024), 256, 0, stream>>>(Wo, wob, (int)SZ_W);

  dim3 gg(32, 16);  // M/128, N/64
  gemm_nt<unsigned short><<<gg, 256, 0, stream>>>(hb, wqb, bq, qb, BT_, E_, E_, 0.125f);
  gemm_nt<unsigned short><<<gg, 256, 0, stream>>>(hb, wkb, bk, kb, BT_, E_, E_, 1.0f);
  gemm_nt<unsigned short><<<gg, 256, 0, stream>>>(hb, wvb, bv, vb, BT_, E_, E_, 1.0f);

  ktv_partial<<<dim3(32, 8), 256, 0, stream>>>(kb, vb, Mpart);
  ktv_reduce<<<32, 256, 0, stream>>>(Mpart, Mfin);
  qm_kernel<<<dim3(128, 16), 256, 0, stream>>>(qb, Mfin, ob);

  gemm_nt<float><<<gg, 256, 0, stream>>>(ob, wob, bo, out, BT_, E_, E_, 1.0f);
}

// Round 2
// 112.013 us; speedup vs baseline: 1.3688x; 1.3688x over previous
//
#include <hip/hip_runtime.h>

#define E_  1024
#define H_  16
#define B_  2
#define T_  2048
#define BT_ (B_*T_)   // 4096

typedef __bf16 bf16x8 __attribute__((ext_vector_type(8)));
typedef float  f32x4  __attribute__((ext_vector_type(4)));
typedef unsigned short u16x8 __attribute__((ext_vector_type(8)));

static __device__ __forceinline__ unsigned short f2bf(float x){
  unsigned int u = __float_as_uint(x);
  u += 0x7fffu + ((u >> 16) & 1u);
  return (unsigned short)(u >> 16);
}
static __device__ __forceinline__ float bf2f(unsigned short s){
  return __uint_as_float(((unsigned int)s) << 16);
}

// async global->LDS, 16B per lane; LDS dest is wave-uniform base + lane*16
static __device__ __forceinline__ void gld16(const unsigned short* g, unsigned short* l){
  __builtin_amdgcn_global_load_lds(
      (const __attribute__((address_space(1))) void*)g,
      (__attribute__((address_space(3))) void*)l, 16, 0, 0);
}

__global__ __launch_bounds__(256)
void cast_hidden(const float* __restrict__ in, unsigned short* __restrict__ out){
  int i = (blockIdx.x * 256 + threadIdx.x) * 8;
  float4 v0 = *(const float4*)(in + i);
  float4 v1 = *(const float4*)(in + i + 4);
  u16x8 o;
  o[0]=f2bf(v0.x); o[1]=f2bf(v0.y); o[2]=f2bf(v0.z); o[3]=f2bf(v0.w);
  o[4]=f2bf(v1.x); o[5]=f2bf(v1.y); o[6]=f2bf(v1.z); o[7]=f2bf(v1.w);
  *(u16x8*)(out + i) = o;
}

// Cast 4 weight matrices: Wq,Wk,Wv -> contiguous wqkv[3*1M], Wo -> wob[1M]
__global__ __launch_bounds__(256)
void cast_weights(const float* __restrict__ Wq, const float* __restrict__ Wk,
                  const float* __restrict__ Wv, const float* __restrict__ Wo,
                  unsigned short* __restrict__ wqkv, unsigned short* __restrict__ wob){
  int bid = blockIdx.x;
  int w = bid >> 9;                                  // 512 blocks per 1M-elem matrix
  int off = (bid & 511) * 2048 + threadIdx.x * 8;
  const float* src = (w==0) ? Wq : (w==1) ? Wk : (w==2) ? Wv : Wo;
  unsigned short* dst = (w==3) ? wob : (wqkv + (size_t)w * 1048576);
  float4 v0 = *(const float4*)(src + off);
  float4 v1 = *(const float4*)(src + off + 4);
  u16x8 o;
  o[0]=f2bf(v0.x); o[1]=f2bf(v0.y); o[2]=f2bf(v0.z); o[3]=f2bf(v0.w);
  o[4]=f2bf(v1.x); o[5]=f2bf(v1.y); o[6]=f2bf(v1.z); o[7]=f2bf(v1.w);
  *(u16x8*)(dst + off) = o;
}

// Fused QKV GEMM: C[i,j] = A[i,:]·Wqkv[j,:] + bias; 128x128 tile, BK=32,
// 4 waves 2x2 (wave tile 64x64 = 4x4 frags), global_load_lds w=16, m97-style.
// N = 3072 split as [Q|K|V]; q gets *0.125 (folded head scaling).
__global__ __launch_bounds__(256)
void gemm_qkv(const unsigned short* __restrict__ A,
              const unsigned short* __restrict__ Wqkv,
              const float* __restrict__ bq, const float* __restrict__ bk,
              const float* __restrict__ bv,
              unsigned short* __restrict__ Q, unsigned short* __restrict__ Ko,
              unsigned short* __restrict__ Vo)
{
  __shared__ unsigned short As[4096];   // 128 rows x 32 cols, linear
  __shared__ unsigned short Bs[4096];
  const int tid = threadIdx.x;
  const int wv = tid >> 6, ln = tid & 63;
  const int wr = wv >> 1, wc = wv & 1;
  const int lr = ln & 15;
  const int lk8 = (ln >> 4) * 8;
  const int bm = blockIdx.x, bn = blockIdx.y;
  const size_t arow0 = (size_t)bm * 128;
  const size_t brow0 = (size_t)bn * 128;
  const int K = 1024;

  f32x4 acc[4][4];
  #pragma unroll
  for (int m = 0; m < 4; ++m)
    #pragma unroll
    for (int n = 0; n < 4; ++n) acc[m][n] = (f32x4){0.f,0.f,0.f,0.f};

  for (int k0 = 0; k0 < K; k0 += 32) {
    #pragma unroll
    for (int i = 0; i < 2; ++i) {
      int c = i*256 + wv*64 + ln;
      int row = c >> 2, off = (c & 3) * 8;
      gld16(A    + (arow0 + row) * K + k0 + off, As + (size_t)(i*256 + wv*64) * 8);
      gld16(Wqkv + (brow0 + row) * K + k0 + off, Bs + (size_t)(i*256 + wv*64) * 8);
    }
    __syncthreads();
    bf16x8 af[4], bf[4];
    #pragma unroll
    for (int m = 0; m < 4; ++m) af[m] = *(const bf16x8*)&As[(wr*64 + m*16 + lr)*32 + lk8];
    #pragma unroll
    for (int n = 0; n < 4; ++n) bf[n] = *(const bf16x8*)&Bs[(wc*64 + n*16 + lr)*32 + lk8];
    #pragma unroll
    for (int m = 0; m < 4; ++m)
      #pragma unroll
      for (int n = 0; n < 4; ++n)
        acc[m][n] = __builtin_amdgcn_mfma_f32_16x16x32_bf16(af[m], bf[n], acc[m][n], 0, 0, 0);
    __syncthreads();
  }

  const int which = bn >> 3;
  const float* bias = (which==0) ? bq : (which==1) ? bk : bv;
  unsigned short* Out = (which==0) ? Q : (which==1) ? Ko : Vo;
  const float scale = (which==0) ? 0.125f : 1.0f;
  #pragma unroll
  for (int n = 0; n < 4; ++n) {
    int col = (bn & 7)*128 + wc*64 + n*16 + lr;
    float bvv = bias[col];
    #pragma unroll
    for (int m = 0; m < 4; ++m) {
      int row0 = bm*128 + wr*64 + m*16 + (ln >> 4) * 4;
      #pragma unroll
      for (int r = 0; r < 4; ++r)
        Out[(size_t)(row0 + r) * 1024 + col] = f2bf((acc[m][n][r] + bvv) * scale);
    }
  }
}

// O-projection GEMM: BM=64 (grid 64x8 = 512 blocks = 2/CU), fp32 output.
__global__ __launch_bounds__(256)
void gemm_o(const unsigned short* __restrict__ A,
            const unsigned short* __restrict__ Bw,
            const float* __restrict__ bias, float* __restrict__ C)
{
  __shared__ unsigned short As[2048];   // 64 x 32
  __shared__ unsigned short Bs[4096];   // 128 x 32
  const int tid = threadIdx.x;
  const int wv = tid >> 6, ln = tid & 63;
  const int wr = wv >> 1, wc = wv & 1;
  const int lr = ln & 15;
  const int lk8 = (ln >> 4) * 8;
  const int bm = blockIdx.x, bn = blockIdx.y;
  const size_t arow0 = (size_t)bm * 64;
  const size_t brow0 = (size_t)bn * 128;
  const int K = 1024;

  f32x4 acc[2][4];
  #pragma unroll
  for (int m = 0; m < 2; ++m)
    #pragma unroll
    for (int n = 0; n < 4; ++n) acc[m][n] = (f32x4){0.f,0.f,0.f,0.f};

  for (int k0 = 0; k0 < K; k0 += 32) {
    { // A: 256 chunks, 1/thread
      int row = tid >> 2, off = (tid & 3) * 8;
      gld16(A + (arow0 + row) * K + k0 + off, As + (size_t)(wv*64) * 8);
    }
    #pragma unroll
    for (int i = 0; i < 2; ++i) {
      int c = i*256 + wv*64 + ln;
      int row = c >> 2, off = (c & 3) * 8;
      gld16(Bw + (brow0 + row) * K + k0 + off, Bs + (size_t)(i*256 + wv*64) * 8);
    }
    __syncthreads();
    bf16x8 af[2], bf[4];
    #pragma unroll
    for (int m = 0; m < 2; ++m) af[m] = *(const bf16x8*)&As[(wr*32 + m*16 + lr)*32 + lk8];
    #pragma unroll
    for (int n = 0; n < 4; ++n) bf[n] = *(const bf16x8*)&Bs[(wc*64 + n*16 + lr)*32 + lk8];
    #pragma unroll
    for (int m = 0; m < 2; ++m)
      #pragma unroll
      for (int n = 0; n < 4; ++n)
        acc[m][n] = __builtin_amdgcn_mfma_f32_16x16x32_bf16(af[m], bf[n], acc[m][n], 0, 0, 0);
    __syncthreads();
  }

  #pragma unroll
  for (int n = 0; n < 4; ++n) {
    int col = bn*128 + wc*64 + n*16 + lr;
    float bvv = bias[col];
    #pragma unroll
    for (int m = 0; m < 2; ++m) {
      int row0 = bm*64 + wr*32 + m*16 + (ln >> 4) * 4;
      #pragma unroll
      for (int r = 0; r < 4; ++r)
        C[(size_t)(row0 + r) * 1024 + col] = acc[m][n][r] + bvv;
    }
  }
}

// Partial M[d1][d2] = sum_{t in chunk} K[b,t,h*64+d1] * V[b,t,h*64+d2]
__global__ __launch_bounds__(256)
void ktv_partial(const unsigned short* __restrict__ Kmat,
                 const unsigned short* __restrict__ Vmat,
                 float* __restrict__ Mpart)
{
  __shared__ float Ks[32][64];
  __shared__ float Vs[32][64];
  const int tid   = threadIdx.x;
  const int bh    = blockIdx.x;   // 0..31
  const int chunk = blockIdx.y;   // 0..7
  const int b = bh >> 4, h = bh & 15;
  const int d2  = tid & 63;
  const int d1b = (tid >> 6) * 16;
  float acc[16];
  #pragma unroll
  for (int i = 0; i < 16; ++i) acc[i] = 0.f;
  const int row = tid >> 3, off = (tid & 7) * 8;
  const size_t base = ((size_t)b * T_) * E_ + (size_t)h * 64;

  for (int t0 = chunk * 256; t0 < chunk * 256 + 256; t0 += 32) {
    u16x8 kv = *(const u16x8*)(Kmat + base + (size_t)(t0 + row) * E_ + off);
    u16x8 vv = *(const u16x8*)(Vmat + base + (size_t)(t0 + row) * E_ + off);
    #pragma unroll
    for (int j = 0; j < 8; ++j) { Ks[row][off+j] = bf2f(kv[j]); Vs[row][off+j] = bf2f(vv[j]); }
    __syncthreads();
    for (int tt = 0; tt < 32; ++tt) {
      float vvv = Vs[tt][d2];
      #pragma unroll
      for (int i = 0; i < 16; ++i) acc[i] += Ks[tt][d1b + i] * vvv;
    }
    __syncthreads();
  }
  float* mp = Mpart + ((size_t)bh * 8 + chunk) * 4096;
  #pragma unroll
  for (int i = 0; i < 16; ++i) mp[(d1b + i) * 64 + d2] = acc[i];
}

__global__ __launch_bounds__(256)
void ktv_reduce(const float* __restrict__ Mpart, float* __restrict__ Mfin){
  const int bh = blockIdx.x;
  for (int i = threadIdx.x; i < 4096; i += 256) {
    float s = 0.f;
    #pragma unroll
    for (int c = 0; c < 8; ++c) s += Mpart[((size_t)bh * 8 + c) * 4096 + i];
    Mfin[(size_t)bh * 4096 + i] = s * 0.125f;
  }
}

__global__ __launch_bounds__(256)
void qm_kernel(const unsigned short* __restrict__ Q,
               const float* __restrict__ Mfin,
               unsigned short* __restrict__ O)
{
  __shared__ float Ms[64][64];
  __shared__ float Qs[32][64];
  const int tid = threadIdx.x;
  const int rb  = blockIdx.x;    // 0..127
  const int h   = blockIdx.y;
  const int b   = rb >> 6;
  const int t0  = (rb & 63) * 32;
  const float* mf = Mfin + ((size_t)(b * 16 + h)) * 4096;
  for (int i = tid; i < 4096; i += 256) Ms[i >> 6][i & 63] = mf[i];
  const int row = tid >> 3, off = (tid & 7) * 8;
  const size_t base = ((size_t)b * T_) * E_ + (size_t)h * 64;
  u16x8 qv = *(const u16x8*)(Q + base + (size_t)(t0 + row) * E_ + off);
  #pragma unroll
  for (int j = 0; j < 8; ++j) Qs[row][off + j] = bf2f(qv[j]);
  __syncthreads();
  const int d2 = tid & 63;
  const int r0 = (tid >> 6) * 8;
  for (int rr = r0; rr < r0 + 8; ++rr) {
    float s = 0.f;
    #pragma unroll
    for (int d1 = 0; d1 < 64; ++d1) s += Qs[rr][d1] * Ms[d1][d2];
    O[base + (size_t)(t0 + rr) * E_ + d2] = f2bf(s);
  }
}

extern "C" void kernel_launch(void* const* d_in, const int* in_sizes, int n_in,
                              void* d_out, int out_size, void* d_ws, size_t ws_size,
                              hipStream_t stream)
{
  const float* hidden = (const float*)d_in[0];
  const float* Wq = (const float*)d_in[1];
  const float* bq = (const float*)d_in[2];
  const float* Wk = (const float*)d_in[3];
  const float* bk = (const float*)d_in[4];
  const float* Wv = (const float*)d_in[5];
  const float* bv = (const float*)d_in[6];
  const float* Wo = (const float*)d_in[7];
  const float* bo = (const float*)d_in[8];
  float* out = (float*)d_out;

  const size_t SZ_ACT = (size_t)BT_ * E_;   // 4M elems
  const size_t SZ_W   = (size_t)E_ * E_;    // 1M elems

  char* p = (char*)d_ws;
  unsigned short* hb   = (unsigned short*)p; p += SZ_ACT * 2;
  unsigned short* wqkv = (unsigned short*)p; p += SZ_W * 3 * 2;
  unsigned short* wob  = (unsigned short*)p; p += SZ_W * 2;
  unsigned short* qb   = (unsigned short*)p; p += SZ_ACT * 2;
  unsigned short* kb   = (unsigned short*)p; p += SZ_ACT * 2;
  unsigned short* vb   = (unsigned short*)p; p += SZ_ACT * 2;
  unsigned short* ob   = (unsigned short*)p; p += SZ_ACT * 2;
  float* Mpart = (float*)p; p += (size_t)32 * 8 * 4096 * 4;
  float* Mfin  = (float*)p; p += (size_t)32 * 4096 * 4;

  cast_hidden <<<2048, 256, 0, stream>>>(hidden, hb);
  cast_weights<<<2048, 256, 0, stream>>>(Wq, Wk, Wv, Wo, wqkv, wob);

  gemm_qkv<<<dim3(32, 24), 256, 0, stream>>>(hb, wqkv, bq, bk, bv, qb, kb, vb);

  ktv_partial<<<dim3(32, 8), 256, 0, stream>>>(kb, vb, Mpart);
  ktv_reduce <<<32, 256, 0, stream>>>(Mpart, Mfin);
  qm_kernel  <<<dim3(128, 16), 256, 0, stream>>>(qb, Mfin, ob);

  gemm_o<<<dim3(64, 8), 256, 0, stream>>>(ob, wob, bo, out);
}